// Round 11
// baseline (268.042 us; speedup 1.0000x reference)
//
#include <hip/hip_runtime.h>
#include <hip/hip_fp16.h>
#include <math.h>

#define ACT_SCALE_F (1.0f / 12.0f)
#define LOG2E_F 1.44269504088896340736f
#define LN2_F   0.69314718055994530942f

typedef __attribute__((ext_vector_type(8))) _Float16 half8;
typedef __attribute__((ext_vector_type(4))) float f32x4;
typedef __attribute__((ext_vector_type(4))) unsigned int uint4v;

// ws layout:
//  float view:
//   [0..127]   Bfq quads {Bf_w[2i], Bf_w[2i+1], Bf_b[i], 0} x32   (legacy, kept)
//   [128..255] B1q   [256..383] B2q   [384..415] spAout[32]
//   [448..449] grad_ref (Bo_w omitted on both sides -> cancels)
//  uint view:
//   [512..2559] matrix fragment table ft: [mv(4)][u(2)][lane(64)] x 4 uints (8 fp16)
//     slot s8 of lane l: k = 16*(s8>>2) + 4*(l>>4) + (s8&3), m_or_n = 16*u + (l&15)
//     mv0=spA1, mv1=spA2 (row-major: fwd A-operand), mv2=spA2^T, mv3=spA1^T (bwd)
//     (R6/R8/R9/R10-proven sigma; used for BOTH operand sides -> cancels vs HW map)
//  float view (new, per-lane bias quad tables in sigma slot order):
//   [2560..4607] Qf: [lane][s8] {Bf_w[2k], Bf_w[2k+1], Bf_b[k], 0},  k = sigma(s8, lane>>4)
//   [4608..6655] Q1: same for B1
//   [6656..8703] Q2: {B2_w[2k], B2_w[2k+1], B2_b[k], spAout[k]}

__device__ __forceinline__ void sp_sig(float x, float& sp, float& sig) {
    float t = __builtin_amdgcn_exp2f(-fabsf(x) * LOG2E_F);
    float u = 1.0f + t;
    float r = __builtin_amdgcn_rcpf(u);
    sp = fmaf(__builtin_amdgcn_logf(u), LN2_F, fmaxf(x, 0.0f));
    sig = (x >= 0.0f) ? r : t * r;
}

__device__ __forceinline__ float sp_only(float x) {
    float t = __builtin_amdgcn_exp2f(-fabsf(x) * LOG2E_F);
    return fmaf(__builtin_amdgcn_logf(1.0f + t), LN2_F, fmaxf(x, 0.0f));
}

__device__ __forceinline__ float sig_only(float x) {
    float t = __builtin_amdgcn_exp2f(-fabsf(x) * LOG2E_F);
    float r = __builtin_amdgcn_rcpf(1.0f + t);
    return (x >= 0.0f) ? r : t * r;
}

__global__ void prep_kernel(const float* __restrict__ Bf_w, const float* __restrict__ Bf_b,
                            const float* __restrict__ A1,
                            const float* __restrict__ B1_w, const float* __restrict__ B1_b,
                            const float* __restrict__ A2,
                            const float* __restrict__ B2_w, const float* __restrict__ B2_b,
                            const float* __restrict__ A_out,
                            float* __restrict__ ws)
{
    __shared__ float sA1[1024], sA2[1024], sAout[32];
    __shared__ float vbufA[32], vbufB[32];
    __shared__ float part0[32], part1[32];
    const int tid = threadIdx.x;  // 64 threads, 1 block

    for (int e = tid; e < 1024; e += 64) {
        sA1[e] = sp_only(A1[e]);
        sA2[e] = sp_only(A2[e]);
    }
    if (tid < 32) {
        float ao = sp_only(A_out[tid]);
        sAout[tid] = ao;
        ws[384 + tid] = ao;
        ws[4 * tid]       = Bf_w[2 * tid];
        ws[4 * tid + 1]   = Bf_w[2 * tid + 1];
        ws[4 * tid + 2]   = Bf_b[tid];
        ws[4 * tid + 3]   = 0.f;
        ws[128 + 4 * tid]     = B1_w[2 * tid];
        ws[128 + 4 * tid + 1] = B1_w[2 * tid + 1];
        ws[128 + 4 * tid + 2] = B1_b[tid];
        ws[128 + 4 * tid + 3] = 0.f;
        ws[256 + 4 * tid]     = B2_w[2 * tid];
        ws[256 + 4 * tid + 1] = B2_w[2 * tid + 1];
        ws[256 + 4 * tid + 2] = B2_b[tid];
        ws[256 + 4 * tid + 3] = 0.f;
    }
    __syncthreads();

    // ---- matrix fragment table (fp16), proven sigma ----
    unsigned int* wsu = (unsigned int*)ws;
    for (int e = tid; e < 512; e += 64) {
        const int mv = e >> 7, u = (e >> 6) & 1, ln = e & 63;
        const int g = ln >> 4, cc = ln & 15, m = 16 * u + cc;
        for (int q = 0; q < 4; ++q) {
            unsigned int word = 0;
            for (int h = 0; h < 2; ++h) {
                const int s8 = 2 * q + h;
                const int k = 16 * (s8 >> 2) + 4 * g + (s8 & 3);
                float v;
                if (mv == 0)      v = sA1[m * 32 + k];
                else if (mv == 1) v = sA2[m * 32 + k];
                else if (mv == 2) v = sA2[k * 32 + m];
                else              v = sA1[k * 32 + m];
                unsigned short hb = __half_as_ushort(__float2half(v));
                word |= ((unsigned int)hb) << (16 * h);
            }
            wsu[512 + 4 * e + q] = word;
        }
    }

    // ---- per-lane bias quad tables in sigma slot order ----
    for (int e = tid; e < 512; e += 64) {
        const int l = e >> 3, s8 = e & 7;
        const int g = l >> 4;
        const int k = 16 * (s8 >> 2) + 4 * g + (s8 & 3);
        ws[2560 + 4 * e]     = Bf_w[2 * k];
        ws[2560 + 4 * e + 1] = Bf_w[2 * k + 1];
        ws[2560 + 4 * e + 2] = Bf_b[k];
        ws[2560 + 4 * e + 3] = 0.f;
        ws[4608 + 4 * e]     = B1_w[2 * k];
        ws[4608 + 4 * e + 1] = B1_w[2 * k + 1];
        ws[4608 + 4 * e + 2] = B1_b[k];
        ws[4608 + 4 * e + 3] = 0.f;
        ws[6656 + 4 * e]     = B2_w[2 * k];
        ws[6656 + 4 * e + 1] = B2_w[2 * k + 1];
        ws[6656 + 4 * e + 2] = B2_b[k];
        ws[6656 + 4 * e + 3] = sAout[k];
    }

    // ---- grad_ref at z0 = 0 ----
    const int i = tid;
    float su1 = 0.f, g1 = 0.f, sb1 = 0.f;
    if (tid < 32) {
        float h0;
        sp_sig(Bf_b[i], h0, su1);
        vbufA[i] = h0;
    }
    __syncthreads();
    if (tid < 32) {
        float a1 = 0.f;
        for (int j = 0; j < 32; ++j) a1 = fmaf(vbufA[j], sA1[i * 32 + j], a1);
        float s1, sa1; sp_sig(a1, s1, sa1);
        g1 = 2.0f * ACT_SCALE_F * s1 * sa1;
        float spb1; sp_sig(B1_b[i], spb1, sb1);
        vbufB[i] = fmaf(ACT_SCALE_F * s1, s1, spb1);   // z1
    }
    __syncthreads();
    if (tid < 32) {
        float a2 = 0.f;
        for (int j = 0; j < 32; ++j) a2 = fmaf(vbufB[j], sA2[i * 32 + j], a2);
        float s2, sa2; sp_sig(a2, s2, sa2);
        float g2 = 2.0f * ACT_SCALE_F * s2 * sa2;
        float sb2 = sig_only(B2_b[i]);
        float ao = sAout[i];
        part0[i] = ao * sb2 * B2_w[i * 2 + 0];
        part1[i] = ao * sb2 * B2_w[i * 2 + 1];
        vbufA[i] = ao * g2;   // v2
    }
    __syncthreads();
    if (tid < 32) {
        float dz1 = 0.f;
        for (int ii = 0; ii < 32; ++ii) dz1 = fmaf(vbufA[ii], sA2[ii * 32 + i], dz1);
        part0[i] += dz1 * sb1 * B1_w[i * 2 + 0];
        part1[i] += dz1 * sb1 * B1_w[i * 2 + 1];
        vbufB[i] = dz1 * g1;   // v1
    }
    __syncthreads();
    if (tid < 32) {
        float dh0 = 0.f;
        for (int ii = 0; ii < 32; ++ii) dh0 = fmaf(vbufB[ii], sA1[ii * 32 + i], dh0);
        part0[i] += dh0 * su1 * Bf_w[i * 2 + 0];
        part1[i] += dh0 * su1 * Bf_w[i * 2 + 1];
    }
    __syncthreads();
    if (tid == 0) {
        float r0 = 0.f, r1 = 0.f;
        for (int j = 0; j < 32; ++j) { r0 += part0[j]; r1 += part1[j]; }
        ws[448] = r0;
        ws[449] = r1;
    }
}

// Zero-LDS main kernel: A-operand = weight fragments (ft table), B-operand =
// per-sample vector fragments chained entirely in registers.
// Lane (c,g): sample = base + c; owns channels m = 16u + 4g + r of its sample
// in every D; D[u][r] feeds B slot s8 = 4u + r of the next MFMA (identity:
// k(s8) = 16*(s8>>2) + 4g + (s8&3) = 16u + 4g + r = m). 16 samples per wave.
__global__ void __launch_bounds__(256) icnn_main(
    const float* __restrict__ eps,
    const float* __restrict__ ws,
    float* __restrict__ out, int n)
{
    const int tid = threadIdx.x;
    const int lane = tid & 63;
    const int wid = tid >> 6;
    const int c = lane & 15;

    int idx = blockIdx.x * 64 + wid * 16 + c;
    if (idx >= n) idx = n - 1;          // branchless clamp

    const uint4v* __restrict__ ft = (const uint4v*)((const unsigned int*)ws + 512);
    const float4* __restrict__ Qf = (const float4*)(ws + 2560) + lane * 8;
    const float4* __restrict__ Q1 = (const float4*)(ws + 4608) + lane * 8;
    const float4* __restrict__ Q2 = (const float4*)(ws + 6656) + lane * 8;
    const float gr0 = ws[448], gr1 = ws[449];

    const float e11 = eps[3 * idx + 0];
    const float e22 = eps[3 * idx + 1];
    const float e12 = eps[3 * idx + 2];
    const float I1 = e11 + e22;
    const float I2 = e11 * e11 + 2.f * e12 * e12 + e22 * e22;

    const f32x4 z4 = {0.f, 0.f, 0.f, 0.f};
    unsigned int bw[4];
    float g1v[8];
    float gx0 = 0.f, gx1 = 0.f;

    // ---- L0: B-frag of h0, built lane-locally ----
    #pragma unroll
    for (int m = 0; m < 4; ++m) {
        float pv0, pv1;
        { const float4 q = Qf[2 * m];     pv0 = sp_only(fmaf(I1, q.x, fmaf(I2, q.y, q.z))); }
        { const float4 q = Qf[2 * m + 1]; pv1 = sp_only(fmaf(I1, q.x, fmaf(I2, q.y, q.z))); }
        bw[m] = __builtin_bit_cast(unsigned int, __floats2half2_rn(pv0, pv1));
    }
    half8 B = __builtin_bit_cast(half8, (uint4v){bw[0], bw[1], bw[2], bw[3]});

    // ---- fwd1: a1 = spA1 @ h0 -> g1 kept, z1 packed ----
    {
        half8 A0 = __builtin_bit_cast(half8, ft[0 * 64 + lane]);
        half8 A1t = __builtin_bit_cast(half8, ft[1 * 64 + lane]);
        f32x4 d0 = __builtin_amdgcn_mfma_f32_16x16x32_f16(A0, B, z4, 0, 0, 0);
        f32x4 d1 = __builtin_amdgcn_mfma_f32_16x16x32_f16(A1t, B, z4, 0, 0, 0);
        #pragma unroll
        for (int m = 0; m < 4; ++m) {
            float pv[2];
            #pragma unroll
            for (int h = 0; h < 2; ++h) {
                const int s8 = 2 * m + h;
                float a = (s8 < 4) ? d0[s8 & 3] : d1[s8 & 3];
                float s1, sg; sp_sig(a, s1, sg);
                g1v[s8] = (2.0f * ACT_SCALE_F) * s1 * sg;
                const float4 q = Q1[s8];
                pv[h] = fmaf(ACT_SCALE_F * s1, s1, sp_only(fmaf(I1, q.x, fmaf(I2, q.y, q.z))));
            }
            bw[m] = __builtin_bit_cast(unsigned int, __floats2half2_rn(pv[0], pv[1]));
        }
        B = __builtin_bit_cast(half8, (uint4v){bw[0], bw[1], bw[2], bw[3]});
    }

    // ---- fwd2: a2 = spA2 @ z1 -> gx(B2) partials, v2 packed ----
    {
        half8 A0 = __builtin_bit_cast(half8, ft[2 * 64 + lane]);
        half8 A1t = __builtin_bit_cast(half8, ft[3 * 64 + lane]);
        f32x4 d0 = __builtin_amdgcn_mfma_f32_16x16x32_f16(A0, B, z4, 0, 0, 0);
        f32x4 d1 = __builtin_amdgcn_mfma_f32_16x16x32_f16(A1t, B, z4, 0, 0, 0);
        #pragma unroll
        for (int m = 0; m < 4; ++m) {
            float pv[2];
            #pragma unroll
            for (int h = 0; h < 2; ++h) {
                const int s8 = 2 * m + h;
                float a = (s8 < 4) ? d0[s8 & 3] : d1[s8 & 3];
                float s2, sg; sp_sig(a, s2, sg);
                const float4 q = Q2[s8];
                float sb2 = sig_only(fmaf(I1, q.x, fmaf(I2, q.y, q.z)));
                float ao = q.w;
                float t = ao * sb2;
                gx0 = fmaf(t, q.x, gx0);
                gx1 = fmaf(t, q.y, gx1);
                pv[h] = ao * (2.0f * ACT_SCALE_F) * s2 * sg;
            }
            bw[m] = __builtin_bit_cast(unsigned int, __floats2half2_rn(pv[0], pv[1]));
        }
        B = __builtin_bit_cast(half8, (uint4v){bw[0], bw[1], bw[2], bw[3]});
    }

    // ---- bwd2: dz1 = spA2^T @ v2 -> gx(B1) partials, v1/64 packed ----
    {
        half8 A0 = __builtin_bit_cast(half8, ft[4 * 64 + lane]);
        half8 A1t = __builtin_bit_cast(half8, ft[5 * 64 + lane]);
        f32x4 d0 = __builtin_amdgcn_mfma_f32_16x16x32_f16(A0, B, z4, 0, 0, 0);
        f32x4 d1 = __builtin_amdgcn_mfma_f32_16x16x32_f16(A1t, B, z4, 0, 0, 0);
        #pragma unroll
        for (int m = 0; m < 4; ++m) {
            float pv[2];
            #pragma unroll
            for (int h = 0; h < 2; ++h) {
                const int s8 = 2 * m + h;
                float dz = (s8 < 4) ? d0[s8 & 3] : d1[s8 & 3];
                const float4 q = Q1[s8];
                float sb1 = sig_only(fmaf(I1, q.x, fmaf(I2, q.y, q.z)));
                float t = dz * sb1;
                gx0 = fmaf(t, q.x, gx0);
                gx1 = fmaf(t, q.y, gx1);
                pv[h] = dz * g1v[s8] * (1.0f / 64.0f);
            }
            bw[m] = __builtin_bit_cast(unsigned int, __floats2half2_rn(pv[0], pv[1]));
        }
        B = __builtin_bit_cast(half8, (uint4v){bw[0], bw[1], bw[2], bw[3]});
    }

    // ---- bwd1: dh0/64 = spA1^T @ v1/64 -> gx(Bf) partials (x64) ----
    {
        half8 A0 = __builtin_bit_cast(half8, ft[6 * 64 + lane]);
        half8 A1t = __builtin_bit_cast(half8, ft[7 * 64 + lane]);
        f32x4 d0 = __builtin_amdgcn_mfma_f32_16x16x32_f16(A0, B, z4, 0, 0, 0);
        f32x4 d1 = __builtin_amdgcn_mfma_f32_16x16x32_f16(A1t, B, z4, 0, 0, 0);
        float gf0 = 0.f, gf1 = 0.f;
        #pragma unroll
        for (int s8 = 0; s8 < 8; ++s8) {
            float dh = (s8 < 4) ? d0[s8 & 3] : d1[s8 & 3];
            const float4 q = Qf[s8];
            float su = sig_only(fmaf(I1, q.x, fmaf(I2, q.y, q.z)));
            float t = dh * su;
            gf0 = fmaf(t, q.x, gf0);
            gf1 = fmaf(t, q.y, gf1);
        }
        gx0 = fmaf(64.f, gf0, gx0);
        gx1 = fmaf(64.f, gf1, gx1);
    }

    // ---- reduce over the 4 g-lanes of this sample ----
    gx0 += __shfl_xor(gx0, 16);
    gx0 += __shfl_xor(gx0, 32);
    gx1 += __shfl_xor(gx1, 16);
    gx1 += __shfl_xor(gx1, 32);

    const float dI1 = gx0 - gr0;
    const float dI2 = gx1 - gr1;
    if (lane < 16) {
        out[3 * idx + 0] = fmaf(2.f * e11, dI2, dI1);
        out[3 * idx + 1] = fmaf(2.f * e22, dI2, dI1);
        out[3 * idx + 2] = 2.f * e12 * dI2;
    }
}

extern "C" void kernel_launch(void* const* d_in, const int* in_sizes, int n_in,
                              void* d_out, int out_size, void* d_ws, size_t ws_size,
                              hipStream_t stream)
{
    const float* eps   = (const float*)d_in[0];
    const float* Bf_w  = (const float*)d_in[1];
    const float* Bf_b  = (const float*)d_in[2];
    const float* A1    = (const float*)d_in[3];
    const float* B1_w  = (const float*)d_in[4];
    const float* B1_b  = (const float*)d_in[5];
    const float* A2    = (const float*)d_in[6];
    const float* B2_w  = (const float*)d_in[7];
    const float* B2_b  = (const float*)d_in[8];
    const float* A_out = (const float*)d_in[9];
    // d_in[10] = Bo_w (cancels in grads - grad_ref), d_in[11] = Bo_b (no grad)

    float* ws  = (float*)d_ws;
    float* out = (float*)d_out;
    const int n = in_sizes[0] / 3;

    prep_kernel<<<1, 64, 0, stream>>>(Bf_w, Bf_b, A1, B1_w, B1_b, A2, B2_w, B2_b, A_out, ws);
    const int blocks = (n + 63) / 64;   // 64 samples per 256-thread block (16 per wave)
    icnn_main<<<blocks, 256, 0, stream>>>(eps, ws, out, n);
}

// Round 12
// 214.496 us; speedup vs baseline: 1.2496x; 1.2496x over previous
//
#include <hip/hip_runtime.h>
#include <hip/hip_fp16.h>
#include <math.h>

#define ACT_SCALE_F (1.0f / 12.0f)
#define LOG2E_F 1.44269504088896340736f
#define LN2_F   0.69314718055994530942f

typedef __attribute__((ext_vector_type(8))) _Float16 half8;
typedef __attribute__((ext_vector_type(4))) float f32x4;
typedef __attribute__((ext_vector_type(4))) unsigned int uint4v;

// ws layout:
//  float view:
//   [0..127]   Bfq quads {Bf_w[2i], Bf_w[2i+1], Bf_b[i], 0} x32   (legacy, kept)
//   [128..255] B1q   [256..383] B2q   [384..415] spAout[32]
//   [448..449] grad_ref (Bo_w omitted on both sides -> cancels)
//  uint view:
//   [512..2559] matrix fragment table ft: [mv(4)][u(2)][lane(64)] x 4 uints (8 fp16)
//     slot s8 of lane l: k = 16*(s8>>2) + 4*(l>>4) + (s8&3), m_or_n = 16*u + (l&15)
//     mv0=spA1, mv1=spA2 (fwd), mv2=spA2^T, mv3=spA1^T (bwd)  [R6..R11-proven sigma]
//  float view (per-lane bias quad tables in sigma slot order):
//   [2560..4607] Qf: [lane][s8] {Bf_w[2k], Bf_w[2k+1], Bf_b[k], 0},  k = sigma(s8, lane>>4)
//   [4608..6655] Q1: same for B1
//   [6656..8703] Q2: {B2_w[2k], B2_w[2k+1], B2_b[k], spAout[k]}

__device__ __forceinline__ void sp_sig(float x, float& sp, float& sig) {
    float t = __builtin_amdgcn_exp2f(-fabsf(x) * LOG2E_F);
    float u = 1.0f + t;
    float r = __builtin_amdgcn_rcpf(u);
    sp = fmaf(__builtin_amdgcn_logf(u), LN2_F, fmaxf(x, 0.0f));
    sig = (x >= 0.0f) ? r : t * r;
}

__device__ __forceinline__ float sp_only(float x) {
    float t = __builtin_amdgcn_exp2f(-fabsf(x) * LOG2E_F);
    return fmaf(__builtin_amdgcn_logf(1.0f + t), LN2_F, fmaxf(x, 0.0f));
}

__device__ __forceinline__ float sig_only(float x) {
    float t = __builtin_amdgcn_exp2f(-fabsf(x) * LOG2E_F);
    float r = __builtin_amdgcn_rcpf(1.0f + t);
    return (x >= 0.0f) ? r : t * r;
}

__global__ void prep_kernel(const float* __restrict__ Bf_w, const float* __restrict__ Bf_b,
                            const float* __restrict__ A1,
                            const float* __restrict__ B1_w, const float* __restrict__ B1_b,
                            const float* __restrict__ A2,
                            const float* __restrict__ B2_w, const float* __restrict__ B2_b,
                            const float* __restrict__ A_out,
                            float* __restrict__ ws)
{
    __shared__ float sA1[1024], sA2[1024], sAout[32];
    __shared__ float vbufA[32], vbufB[32];
    __shared__ float part0[32], part1[32];
    const int tid = threadIdx.x;  // 64 threads, 1 block

    for (int e = tid; e < 1024; e += 64) {
        sA1[e] = sp_only(A1[e]);
        sA2[e] = sp_only(A2[e]);
    }
    if (tid < 32) {
        float ao = sp_only(A_out[tid]);
        sAout[tid] = ao;
        ws[384 + tid] = ao;
        ws[4 * tid]       = Bf_w[2 * tid];
        ws[4 * tid + 1]   = Bf_w[2 * tid + 1];
        ws[4 * tid + 2]   = Bf_b[tid];
        ws[4 * tid + 3]   = 0.f;
        ws[128 + 4 * tid]     = B1_w[2 * tid];
        ws[128 + 4 * tid + 1] = B1_w[2 * tid + 1];
        ws[128 + 4 * tid + 2] = B1_b[tid];
        ws[128 + 4 * tid + 3] = 0.f;
        ws[256 + 4 * tid]     = B2_w[2 * tid];
        ws[256 + 4 * tid + 1] = B2_w[2 * tid + 1];
        ws[256 + 4 * tid + 2] = B2_b[tid];
        ws[256 + 4 * tid + 3] = 0.f;
    }
    __syncthreads();

    // ---- matrix fragment table (fp16), proven sigma ----
    unsigned int* wsu = (unsigned int*)ws;
    for (int e = tid; e < 512; e += 64) {
        const int mv = e >> 7, u = (e >> 6) & 1, ln = e & 63;
        const int g = ln >> 4, cc = ln & 15, m = 16 * u + cc;
        for (int q = 0; q < 4; ++q) {
            unsigned int word = 0;
            for (int h = 0; h < 2; ++h) {
                const int s8 = 2 * q + h;
                const int k = 16 * (s8 >> 2) + 4 * g + (s8 & 3);
                float v;
                if (mv == 0)      v = sA1[m * 32 + k];
                else if (mv == 1) v = sA2[m * 32 + k];
                else if (mv == 2) v = sA2[k * 32 + m];
                else              v = sA1[k * 32 + m];
                unsigned short hb = __half_as_ushort(__float2half(v));
                word |= ((unsigned int)hb) << (16 * h);
            }
            wsu[512 + 4 * e + q] = word;
        }
    }

    // ---- per-lane bias quad tables in sigma slot order ----
    for (int e = tid; e < 512; e += 64) {
        const int l = e >> 3, s8 = e & 7;
        const int g = l >> 4;
        const int k = 16 * (s8 >> 2) + 4 * g + (s8 & 3);
        ws[2560 + 4 * e]     = Bf_w[2 * k];
        ws[2560 + 4 * e + 1] = Bf_w[2 * k + 1];
        ws[2560 + 4 * e + 2] = Bf_b[k];
        ws[2560 + 4 * e + 3] = 0.f;
        ws[4608 + 4 * e]     = B1_w[2 * k];
        ws[4608 + 4 * e + 1] = B1_w[2 * k + 1];
        ws[4608 + 4 * e + 2] = B1_b[k];
        ws[4608 + 4 * e + 3] = 0.f;
        ws[6656 + 4 * e]     = B2_w[2 * k];
        ws[6656 + 4 * e + 1] = B2_w[2 * k + 1];
        ws[6656 + 4 * e + 2] = B2_b[k];
        ws[6656 + 4 * e + 3] = sAout[k];
    }

    // ---- grad_ref at z0 = 0 ----
    const int i = tid;
    float su1 = 0.f, g1 = 0.f, sb1 = 0.f;
    if (tid < 32) {
        float h0;
        sp_sig(Bf_b[i], h0, su1);
        vbufA[i] = h0;
    }
    __syncthreads();
    if (tid < 32) {
        float a1 = 0.f;
        for (int j = 0; j < 32; ++j) a1 = fmaf(vbufA[j], sA1[i * 32 + j], a1);
        float s1, sa1; sp_sig(a1, s1, sa1);
        g1 = 2.0f * ACT_SCALE_F * s1 * sa1;
        float spb1; sp_sig(B1_b[i], spb1, sb1);
        vbufB[i] = fmaf(ACT_SCALE_F * s1, s1, spb1);   // z1
    }
    __syncthreads();
    if (tid < 32) {
        float a2 = 0.f;
        for (int j = 0; j < 32; ++j) a2 = fmaf(vbufB[j], sA2[i * 32 + j], a2);
        float s2, sa2; sp_sig(a2, s2, sa2);
        float g2 = 2.0f * ACT_SCALE_F * s2 * sa2;
        float sb2 = sig_only(B2_b[i]);
        float ao = sAout[i];
        part0[i] = ao * sb2 * B2_w[i * 2 + 0];
        part1[i] = ao * sb2 * B2_w[i * 2 + 1];
        vbufA[i] = ao * g2;   // v2
    }
    __syncthreads();
    if (tid < 32) {
        float dz1 = 0.f;
        for (int ii = 0; ii < 32; ++ii) dz1 = fmaf(vbufA[ii], sA2[ii * 32 + i], dz1);
        part0[i] += dz1 * sb1 * B1_w[i * 2 + 0];
        part1[i] += dz1 * sb1 * B1_w[i * 2 + 1];
        vbufB[i] = dz1 * g1;   // v1
    }
    __syncthreads();
    if (tid < 32) {
        float dh0 = 0.f;
        for (int ii = 0; ii < 32; ++ii) dh0 = fmaf(vbufB[ii], sA1[ii * 32 + i], dh0);
        part0[i] += dh0 * su1 * Bf_w[i * 2 + 0];
        part1[i] += dh0 * su1 * Bf_w[i * 2 + 1];
    }
    __syncthreads();
    if (tid == 0) {
        float r0 = 0.f, r1 = 0.f;
        for (int j = 0; j < 32; ++j) { r0 += part0[j]; r1 += part1[j]; }
        ws[448] = r0;
        ws[449] = r1;
    }
}

// Zero-LDS register-chain kernel (R11 identity, verified) + R12 change:
// cache bwd multipliers at fwd time so bwd phases touch NO memory.
// Lane (c,g): sample c; D[u][r] feeds B slot s8=4u+r of the next MFMA.
__global__ void __launch_bounds__(256, 4) icnn_main(
    const float* __restrict__ eps,
    const float* __restrict__ ws,
    float* __restrict__ out, int n)
{
    const int tid = threadIdx.x;
    const int lane = tid & 63;
    const int wid = tid >> 6;
    const int c = lane & 15;

    int idx = blockIdx.x * 64 + wid * 16 + c;
    if (idx >= n) idx = n - 1;          // branchless clamp

    const uint4v* __restrict__ ft = (const uint4v*)((const unsigned int*)ws + 512);
    const float4* __restrict__ Qf = (const float4*)(ws + 2560) + lane * 8;
    const float4* __restrict__ Q1 = (const float4*)(ws + 4608) + lane * 8;
    const float4* __restrict__ Q2 = (const float4*)(ws + 6656) + lane * 8;
    const float gr0 = ws[448], gr1 = ws[449];

    const float e11 = eps[3 * idx + 0];
    const float e22 = eps[3 * idx + 1];
    const float e12 = eps[3 * idx + 2];
    const float I1 = e11 + e22;
    const float I2 = e11 * e11 + 2.f * e12 * e12 + e22 * e22;

    const f32x4 z4 = {0.f, 0.f, 0.f, 0.f};
    unsigned int bw[4];
    float g1v[8];                      // 2*ACT_SCALE * s1 * sig(a1)
    float sufx[8], sufy[8];            // sig(u_f) * {qf.x, qf.y}
    float sb1x[8], sb1y[8];            // sig(b1) * {q1.x, q1.y}
    float gx0 = 0.f, gx1 = 0.f;

    // ---- L0: B-frag of h0; cache su*qf ----
    #pragma unroll
    for (int m = 0; m < 4; ++m) {
        float pv[2];
        #pragma unroll
        for (int h = 0; h < 2; ++h) {
            const int s8 = 2 * m + h;
            const float4 q = Qf[s8];
            float h0, su;
            sp_sig(fmaf(I1, q.x, fmaf(I2, q.y, q.z)), h0, su);
            sufx[s8] = su * q.x;
            sufy[s8] = su * q.y;
            pv[h] = h0;
        }
        bw[m] = __builtin_bit_cast(unsigned int, __floats2half2_rn(pv[0], pv[1]));
    }
    half8 B = __builtin_bit_cast(half8, (uint4v){bw[0], bw[1], bw[2], bw[3]});

    // ---- fwd1: a1 = spA1 @ h0 -> keep g1, sb1*q1; z1 packed ----
    {
        half8 A0 = __builtin_bit_cast(half8, ft[0 * 64 + lane]);
        half8 A1t = __builtin_bit_cast(half8, ft[1 * 64 + lane]);
        f32x4 d0 = __builtin_amdgcn_mfma_f32_16x16x32_f16(A0, B, z4, 0, 0, 0);
        f32x4 d1 = __builtin_amdgcn_mfma_f32_16x16x32_f16(A1t, B, z4, 0, 0, 0);
        #pragma unroll
        for (int m = 0; m < 4; ++m) {
            float pv[2];
            #pragma unroll
            for (int h = 0; h < 2; ++h) {
                const int s8 = 2 * m + h;
                float a = (s8 < 4) ? d0[s8 & 3] : d1[s8 & 3];
                float s1, sg; sp_sig(a, s1, sg);
                g1v[s8] = (2.0f * ACT_SCALE_F) * s1 * sg;
                const float4 q = Q1[s8];
                float spb1, sb1;
                sp_sig(fmaf(I1, q.x, fmaf(I2, q.y, q.z)), spb1, sb1);
                sb1x[s8] = sb1 * q.x;
                sb1y[s8] = sb1 * q.y;
                pv[h] = fmaf(ACT_SCALE_F * s1, s1, spb1);
            }
            bw[m] = __builtin_bit_cast(unsigned int, __floats2half2_rn(pv[0], pv[1]));
        }
        B = __builtin_bit_cast(half8, (uint4v){bw[0], bw[1], bw[2], bw[3]});
    }

    // ---- fwd2: a2 = spA2 @ z1 -> gx(B2) partials; v2 packed ----
    {
        half8 A0 = __builtin_bit_cast(half8, ft[2 * 64 + lane]);
        half8 A1t = __builtin_bit_cast(half8, ft[3 * 64 + lane]);
        f32x4 d0 = __builtin_amdgcn_mfma_f32_16x16x32_f16(A0, B, z4, 0, 0, 0);
        f32x4 d1 = __builtin_amdgcn_mfma_f32_16x16x32_f16(A1t, B, z4, 0, 0, 0);
        #pragma unroll
        for (int m = 0; m < 4; ++m) {
            float pv[2];
            #pragma unroll
            for (int h = 0; h < 2; ++h) {
                const int s8 = 2 * m + h;
                float a = (s8 < 4) ? d0[s8 & 3] : d1[s8 & 3];
                float s2, sg; sp_sig(a, s2, sg);
                const float4 q = Q2[s8];
                float sb2 = sig_only(fmaf(I1, q.x, fmaf(I2, q.y, q.z)));
                float ao = q.w;
                float t = ao * sb2;
                gx0 = fmaf(t, q.x, gx0);
                gx1 = fmaf(t, q.y, gx1);
                pv[h] = ao * (2.0f * ACT_SCALE_F) * s2 * sg;
            }
            bw[m] = __builtin_bit_cast(unsigned int, __floats2half2_rn(pv[0], pv[1]));
        }
        B = __builtin_bit_cast(half8, (uint4v){bw[0], bw[1], bw[2], bw[3]});
    }

    // ---- bwd2: dz1 = spA2^T @ v2 -> registers only ----
    {
        half8 A0 = __builtin_bit_cast(half8, ft[4 * 64 + lane]);
        half8 A1t = __builtin_bit_cast(half8, ft[5 * 64 + lane]);
        f32x4 d0 = __builtin_amdgcn_mfma_f32_16x16x32_f16(A0, B, z4, 0, 0, 0);
        f32x4 d1 = __builtin_amdgcn_mfma_f32_16x16x32_f16(A1t, B, z4, 0, 0, 0);
        #pragma unroll
        for (int m = 0; m < 4; ++m) {
            float pv[2];
            #pragma unroll
            for (int h = 0; h < 2; ++h) {
                const int s8 = 2 * m + h;
                float dz = (s8 < 4) ? d0[s8 & 3] : d1[s8 & 3];
                gx0 = fmaf(dz, sb1x[s8], gx0);
                gx1 = fmaf(dz, sb1y[s8], gx1);
                pv[h] = dz * g1v[s8] * (1.0f / 64.0f);
            }
            bw[m] = __builtin_bit_cast(unsigned int, __floats2half2_rn(pv[0], pv[1]));
        }
        B = __builtin_bit_cast(half8, (uint4v){bw[0], bw[1], bw[2], bw[3]});
    }

    // ---- bwd1: dh0/64 = spA1^T @ v1/64 -> registers only (x64) ----
    {
        half8 A0 = __builtin_bit_cast(half8, ft[6 * 64 + lane]);
        half8 A1t = __builtin_bit_cast(half8, ft[7 * 64 + lane]);
        f32x4 d0 = __builtin_amdgcn_mfma_f32_16x16x32_f16(A0, B, z4, 0, 0, 0);
        f32x4 d1 = __builtin_amdgcn_mfma_f32_16x16x32_f16(A1t, B, z4, 0, 0, 0);
        float gf0 = 0.f, gf1 = 0.f;
        #pragma unroll
        for (int s8 = 0; s8 < 8; ++s8) {
            float dh = (s8 < 4) ? d0[s8 & 3] : d1[s8 & 3];
            gf0 = fmaf(dh, sufx[s8], gf0);
            gf1 = fmaf(dh, sufy[s8], gf1);
        }
        gx0 = fmaf(64.f, gf0, gx0);
        gx1 = fmaf(64.f, gf1, gx1);
    }

    // ---- reduce over the 4 g-lanes of this sample ----
    gx0 += __shfl_xor(gx0, 16);
    gx0 += __shfl_xor(gx0, 32);
    gx1 += __shfl_xor(gx1, 16);
    gx1 += __shfl_xor(gx1, 32);

    const float dI1 = gx0 - gr0;
    const float dI2 = gx1 - gr1;
    if (lane < 16) {
        out[3 * idx + 0] = fmaf(2.f * e11, dI2, dI1);
        out[3 * idx + 1] = fmaf(2.f * e22, dI2, dI1);
        out[3 * idx + 2] = 2.f * e12 * dI2;
    }
}

extern "C" void kernel_launch(void* const* d_in, const int* in_sizes, int n_in,
                              void* d_out, int out_size, void* d_ws, size_t ws_size,
                              hipStream_t stream)
{
    const float* eps   = (const float*)d_in[0];
    const float* Bf_w  = (const float*)d_in[1];
    const float* Bf_b  = (const float*)d_in[2];
    const float* A1    = (const float*)d_in[3];
    const float* B1_w  = (const float*)d_in[4];
    const float* B1_b  = (const float*)d_in[5];
    const float* A2    = (const float*)d_in[6];
    const float* B2_w  = (const float*)d_in[7];
    const float* B2_b  = (const float*)d_in[8];
    const float* A_out = (const float*)d_in[9];
    // d_in[10] = Bo_w (cancels in grads - grad_ref), d_in[11] = Bo_b (no grad)

    float* ws  = (float*)d_ws;
    float* out = (float*)d_out;
    const int n = in_sizes[0] / 3;

    prep_kernel<<<1, 64, 0, stream>>>(Bf_w, Bf_b, A1, B1_w, B1_b, A2, B2_w, B2_b, A_out, ws);
    const int blocks = (n + 63) / 64;   // 64 samples per 256-thread block (16 per wave)
    icnn_main<<<blocks, 256, 0, stream>>>(eps, ws, out, n);
}

// Round 13
// 212.151 us; speedup vs baseline: 1.2634x; 1.0111x over previous
//
#include <hip/hip_runtime.h>
#include <hip/hip_fp16.h>
#include <math.h>

#define ACT_SCALE_F (1.0f / 12.0f)
#define LOG2E_F 1.44269504088896340736f
#define LN2_F   0.69314718055994530942f

typedef __attribute__((ext_vector_type(8))) _Float16 half8;
typedef __attribute__((ext_vector_type(4))) float f32x4;
typedef __attribute__((ext_vector_type(4))) unsigned int uint4v;

// ws layout:
//  float view:
//   [0..127]   Bfq quads (legacy)   [128..255] B1q   [256..383] B2q   [384..415] spAout
//   [448..449] grad_ref (Bo_w omitted on both sides -> cancels)
//  uint view:
//   [512..2559] matrix fragment table ft: [mv(4)][u(2)][lane(64)] x 4 uints (8 fp16)
//     slot s8 of lane l: k = 16*(s8>>2) + 4*(l>>4) + (s8&3), m_or_n = 16*u + (l&15)
//     mv0=spA1, mv1=spA2 (fwd), mv2=spA2^T, mv3=spA1^T (bwd)  [R6..R12-proven sigma]
//  float view (per-lane bias quad tables in sigma slot order):
//   [2560..4607] Qf: [lane][s8] {Bf_w[2k], Bf_w[2k+1], Bf_b[k], 0},  k = sigma(s8, lane>>4)
//   [4608..6655] Q1: same for B1
//   [6656..8703] Q2: {B2_w[2k], B2_w[2k+1], B2_b[k], spAout[k]}

__device__ __forceinline__ void sp_sig(float x, float& sp, float& sig) {
    float t = __builtin_amdgcn_exp2f(-fabsf(x) * LOG2E_F);
    float u = 1.0f + t;
    float r = __builtin_amdgcn_rcpf(u);
    sp = fmaf(__builtin_amdgcn_logf(u), LN2_F, fmaxf(x, 0.0f));
    sig = (x >= 0.0f) ? r : t * r;
}

__device__ __forceinline__ float sp_only(float x) {
    float t = __builtin_amdgcn_exp2f(-fabsf(x) * LOG2E_F);
    return fmaf(__builtin_amdgcn_logf(1.0f + t), LN2_F, fmaxf(x, 0.0f));
}

__device__ __forceinline__ float sig_only(float x) {
    float t = __builtin_amdgcn_exp2f(-fabsf(x) * LOG2E_F);
    float r = __builtin_amdgcn_rcpf(1.0f + t);
    return (x >= 0.0f) ? r : t * r;
}

__global__ void prep_kernel(const float* __restrict__ Bf_w, const float* __restrict__ Bf_b,
                            const float* __restrict__ A1,
                            const float* __restrict__ B1_w, const float* __restrict__ B1_b,
                            const float* __restrict__ A2,
                            const float* __restrict__ B2_w, const float* __restrict__ B2_b,
                            const float* __restrict__ A_out,
                            float* __restrict__ ws)
{
    __shared__ float sA1[1024], sA2[1024], sAout[32];
    __shared__ float vbufA[32], vbufB[32];
    __shared__ float part0[32], part1[32];
    const int tid = threadIdx.x;  // 64 threads, 1 block

    for (int e = tid; e < 1024; e += 64) {
        sA1[e] = sp_only(A1[e]);
        sA2[e] = sp_only(A2[e]);
    }
    if (tid < 32) {
        float ao = sp_only(A_out[tid]);
        sAout[tid] = ao;
        ws[384 + tid] = ao;
    }
    __syncthreads();

    // ---- matrix fragment table (fp16), proven sigma ----
    unsigned int* wsu = (unsigned int*)ws;
    for (int e = tid; e < 512; e += 64) {
        const int mv = e >> 7, u = (e >> 6) & 1, ln = e & 63;
        const int g = ln >> 4, cc = ln & 15, m = 16 * u + cc;
        for (int q = 0; q < 4; ++q) {
            unsigned int word = 0;
            for (int h = 0; h < 2; ++h) {
                const int s8 = 2 * q + h;
                const int k = 16 * (s8 >> 2) + 4 * g + (s8 & 3);
                float v;
                if (mv == 0)      v = sA1[m * 32 + k];
                else if (mv == 1) v = sA2[m * 32 + k];
                else if (mv == 2) v = sA2[k * 32 + m];
                else              v = sA1[k * 32 + m];
                unsigned short hb = __half_as_ushort(__float2half(v));
                word |= ((unsigned int)hb) << (16 * h);
            }
            wsu[512 + 4 * e + q] = word;
        }
    }

    // ---- per-lane bias quad tables in sigma slot order ----
    for (int e = tid; e < 512; e += 64) {
        const int l = e >> 3, s8 = e & 7;
        const int g = l >> 4;
        const int k = 16 * (s8 >> 2) + 4 * g + (s8 & 3);
        ws[2560 + 4 * e]     = Bf_w[2 * k];
        ws[2560 + 4 * e + 1] = Bf_w[2 * k + 1];
        ws[2560 + 4 * e + 2] = Bf_b[k];
        ws[2560 + 4 * e + 3] = 0.f;
        ws[4608 + 4 * e]     = B1_w[2 * k];
        ws[4608 + 4 * e + 1] = B1_w[2 * k + 1];
        ws[4608 + 4 * e + 2] = B1_b[k];
        ws[4608 + 4 * e + 3] = 0.f;
        ws[6656 + 4 * e]     = B2_w[2 * k];
        ws[6656 + 4 * e + 1] = B2_w[2 * k + 1];
        ws[6656 + 4 * e + 2] = B2_b[k];
        ws[6656 + 4 * e + 3] = sAout[k];
    }

    // ---- grad_ref at z0 = 0 ----
    const int i = tid;
    float su1 = 0.f, g1 = 0.f, sb1 = 0.f;
    if (tid < 32) {
        float h0;
        sp_sig(Bf_b[i], h0, su1);
        vbufA[i] = h0;
    }
    __syncthreads();
    if (tid < 32) {
        float a1 = 0.f;
        for (int j = 0; j < 32; ++j) a1 = fmaf(vbufA[j], sA1[i * 32 + j], a1);
        float s1, sa1; sp_sig(a1, s1, sa1);
        g1 = 2.0f * ACT_SCALE_F * s1 * sa1;
        float spb1; sp_sig(B1_b[i], spb1, sb1);
        vbufB[i] = fmaf(ACT_SCALE_F * s1, s1, spb1);   // z1
    }
    __syncthreads();
    if (tid < 32) {
        float a2 = 0.f;
        for (int j = 0; j < 32; ++j) a2 = fmaf(vbufB[j], sA2[i * 32 + j], a2);
        float s2, sa2; sp_sig(a2, s2, sa2);
        float g2 = 2.0f * ACT_SCALE_F * s2 * sa2;
        float sb2 = sig_only(B2_b[i]);
        float ao = sAout[i];
        part0[i] = ao * sb2 * B2_w[i * 2 + 0];
        part1[i] = ao * sb2 * B2_w[i * 2 + 1];
        vbufA[i] = ao * g2;   // v2
    }
    __syncthreads();
    if (tid < 32) {
        float dz1 = 0.f;
        for (int ii = 0; ii < 32; ++ii) dz1 = fmaf(vbufA[ii], sA2[ii * 32 + i], dz1);
        part0[i] += dz1 * sb1 * B1_w[i * 2 + 0];
        part1[i] += dz1 * sb1 * B1_w[i * 2 + 1];
        vbufB[i] = dz1 * g1;   // v1
    }
    __syncthreads();
    if (tid < 32) {
        float dh0 = 0.f;
        for (int ii = 0; ii < 32; ++ii) dh0 = fmaf(vbufB[ii], sA1[ii * 32 + i], dh0);
        part0[i] += dh0 * su1 * Bf_w[i * 2 + 0];
        part1[i] += dh0 * su1 * Bf_w[i * 2 + 1];
    }
    __syncthreads();
    if (tid == 0) {
        float r0 = 0.f, r1 = 0.f;
        for (int j = 0; j < 32; ++j) { r0 += part0[j]; r1 += part1[j]; }
        ws[448] = r0;
        ws[449] = r1;
    }
}

// Zero-LDS register-chain kernel (R11/R12 identity + cached bwd multipliers),
// R13 change: SINGLE-WAVE blocks -> compiler allocates ~128 VGPR (R10-proven
// heuristic), eliminating R12's scratch spill. 16 samples per wave/block.
__global__ void __launch_bounds__(64, 2) icnn_main(
    const float* __restrict__ eps,
    const float* __restrict__ ws,
    float* __restrict__ out, int n)
{
    const int lane = threadIdx.x;       // one wave
    const int c = lane & 15;

    int idx = blockIdx.x * 16 + c;
    if (idx >= n) idx = n - 1;          // branchless clamp

    const uint4v* __restrict__ ft = (const uint4v*)((const unsigned int*)ws + 512);
    const float4* __restrict__ Qf = (const float4*)(ws + 2560) + lane * 8;
    const float4* __restrict__ Q1 = (const float4*)(ws + 4608) + lane * 8;
    const float4* __restrict__ Q2 = (const float4*)(ws + 6656) + lane * 8;
    const float gr0 = ws[448], gr1 = ws[449];

    const float e11 = eps[3 * idx + 0];
    const float e22 = eps[3 * idx + 1];
    const float e12 = eps[3 * idx + 2];
    const float I1 = e11 + e22;
    const float I2 = e11 * e11 + 2.f * e12 * e12 + e22 * e22;

    const f32x4 z4 = {0.f, 0.f, 0.f, 0.f};
    unsigned int bw[4];
    float g1v[8];                      // 2*ACT_SCALE * s1 * sig(a1)
    float sufx[8], sufy[8];            // sig(u_f) * {qf.x, qf.y}
    float sb1x[8], sb1y[8];            // sig(b1) * {q1.x, q1.y}
    float gx0 = 0.f, gx1 = 0.f;

    // ---- L0: B-frag of h0; cache su*qf ----
    #pragma unroll
    for (int m = 0; m < 4; ++m) {
        float pv[2];
        #pragma unroll
        for (int h = 0; h < 2; ++h) {
            const int s8 = 2 * m + h;
            const float4 q = Qf[s8];
            float h0, su;
            sp_sig(fmaf(I1, q.x, fmaf(I2, q.y, q.z)), h0, su);
            sufx[s8] = su * q.x;
            sufy[s8] = su * q.y;
            pv[h] = h0;
        }
        bw[m] = __builtin_bit_cast(unsigned int, __floats2half2_rn(pv[0], pv[1]));
    }
    half8 B = __builtin_bit_cast(half8, (uint4v){bw[0], bw[1], bw[2], bw[3]});

    // ---- fwd1: a1 = spA1 @ h0 -> keep g1, sb1*q1; z1 packed ----
    {
        half8 A0 = __builtin_bit_cast(half8, ft[0 * 64 + lane]);
        half8 A1t = __builtin_bit_cast(half8, ft[1 * 64 + lane]);
        f32x4 d0 = __builtin_amdgcn_mfma_f32_16x16x32_f16(A0, B, z4, 0, 0, 0);
        f32x4 d1 = __builtin_amdgcn_mfma_f32_16x16x32_f16(A1t, B, z4, 0, 0, 0);
        #pragma unroll
        for (int m = 0; m < 4; ++m) {
            float pv[2];
            #pragma unroll
            for (int h = 0; h < 2; ++h) {
                const int s8 = 2 * m + h;
                float a = (s8 < 4) ? d0[s8 & 3] : d1[s8 & 3];
                float s1, sg; sp_sig(a, s1, sg);
                g1v[s8] = (2.0f * ACT_SCALE_F) * s1 * sg;
                const float4 q = Q1[s8];
                float spb1, sb1;
                sp_sig(fmaf(I1, q.x, fmaf(I2, q.y, q.z)), spb1, sb1);
                sb1x[s8] = sb1 * q.x;
                sb1y[s8] = sb1 * q.y;
                pv[h] = fmaf(ACT_SCALE_F * s1, s1, spb1);
            }
            bw[m] = __builtin_bit_cast(unsigned int, __floats2half2_rn(pv[0], pv[1]));
        }
        B = __builtin_bit_cast(half8, (uint4v){bw[0], bw[1], bw[2], bw[3]});
    }

    // ---- fwd2: a2 = spA2 @ z1 -> gx(B2) partials; v2 packed ----
    {
        half8 A0 = __builtin_bit_cast(half8, ft[2 * 64 + lane]);
        half8 A1t = __builtin_bit_cast(half8, ft[3 * 64 + lane]);
        f32x4 d0 = __builtin_amdgcn_mfma_f32_16x16x32_f16(A0, B, z4, 0, 0, 0);
        f32x4 d1 = __builtin_amdgcn_mfma_f32_16x16x32_f16(A1t, B, z4, 0, 0, 0);
        #pragma unroll
        for (int m = 0; m < 4; ++m) {
            float pv[2];
            #pragma unroll
            for (int h = 0; h < 2; ++h) {
                const int s8 = 2 * m + h;
                float a = (s8 < 4) ? d0[s8 & 3] : d1[s8 & 3];
                float s2, sg; sp_sig(a, s2, sg);
                const float4 q = Q2[s8];
                float sb2 = sig_only(fmaf(I1, q.x, fmaf(I2, q.y, q.z)));
                float ao = q.w;
                float t = ao * sb2;
                gx0 = fmaf(t, q.x, gx0);
                gx1 = fmaf(t, q.y, gx1);
                pv[h] = ao * (2.0f * ACT_SCALE_F) * s2 * sg;
            }
            bw[m] = __builtin_bit_cast(unsigned int, __floats2half2_rn(pv[0], pv[1]));
        }
        B = __builtin_bit_cast(half8, (uint4v){bw[0], bw[1], bw[2], bw[3]});
    }

    // ---- bwd2: dz1 = spA2^T @ v2 -> registers only ----
    {
        half8 A0 = __builtin_bit_cast(half8, ft[4 * 64 + lane]);
        half8 A1t = __builtin_bit_cast(half8, ft[5 * 64 + lane]);
        f32x4 d0 = __builtin_amdgcn_mfma_f32_16x16x32_f16(A0, B, z4, 0, 0, 0);
        f32x4 d1 = __builtin_amdgcn_mfma_f32_16x16x32_f16(A1t, B, z4, 0, 0, 0);
        #pragma unroll
        for (int m = 0; m < 4; ++m) {
            float pv[2];
            #pragma unroll
            for (int h = 0; h < 2; ++h) {
                const int s8 = 2 * m + h;
                float dz = (s8 < 4) ? d0[s8 & 3] : d1[s8 & 3];
                gx0 = fmaf(dz, sb1x[s8], gx0);
                gx1 = fmaf(dz, sb1y[s8], gx1);
                pv[h] = dz * g1v[s8] * (1.0f / 64.0f);
            }
            bw[m] = __builtin_bit_cast(unsigned int, __floats2half2_rn(pv[0], pv[1]));
        }
        B = __builtin_bit_cast(half8, (uint4v){bw[0], bw[1], bw[2], bw[3]});
    }

    // ---- bwd1: dh0/64 = spA1^T @ v1/64 -> registers only (x64) ----
    {
        half8 A0 = __builtin_bit_cast(half8, ft[6 * 64 + lane]);
        half8 A1t = __builtin_bit_cast(half8, ft[7 * 64 + lane]);
        f32x4 d0 = __builtin_amdgcn_mfma_f32_16x16x32_f16(A0, B, z4, 0, 0, 0);
        f32x4 d1 = __builtin_amdgcn_mfma_f32_16x16x32_f16(A1t, B, z4, 0, 0, 0);
        float gf0 = 0.f, gf1 = 0.f;
        #pragma unroll
        for (int s8 = 0; s8 < 8; ++s8) {
            float dh = (s8 < 4) ? d0[s8 & 3] : d1[s8 & 3];
            gf0 = fmaf(dh, sufx[s8], gf0);
            gf1 = fmaf(dh, sufy[s8], gf1);
        }
        gx0 = fmaf(64.f, gf0, gx0);
        gx1 = fmaf(64.f, gf1, gx1);
    }

    // ---- reduce over the 4 g-lanes of this sample ----
    gx0 += __shfl_xor(gx0, 16);
    gx0 += __shfl_xor(gx0, 32);
    gx1 += __shfl_xor(gx1, 16);
    gx1 += __shfl_xor(gx1, 32);

    const float dI1 = gx0 - gr0;
    const float dI2 = gx1 - gr1;
    if (lane < 16) {
        out[3 * idx + 0] = fmaf(2.f * e11, dI2, dI1);
        out[3 * idx + 1] = fmaf(2.f * e22, dI2, dI1);
        out[3 * idx + 2] = 2.f * e12 * dI2;
    }
}

extern "C" void kernel_launch(void* const* d_in, const int* in_sizes, int n_in,
                              void* d_out, int out_size, void* d_ws, size_t ws_size,
                              hipStream_t stream)
{
    const float* eps   = (const float*)d_in[0];
    const float* Bf_w  = (const float*)d_in[1];
    const float* Bf_b  = (const float*)d_in[2];
    const float* A1    = (const float*)d_in[3];
    const float* B1_w  = (const float*)d_in[4];
    const float* B1_b  = (const float*)d_in[5];
    const float* A2    = (const float*)d_in[6];
    const float* B2_w  = (const float*)d_in[7];
    const float* B2_b  = (const float*)d_in[8];
    const float* A_out = (const float*)d_in[9];
    // d_in[10] = Bo_w (cancels in grads - grad_ref), d_in[11] = Bo_b (no grad)

    float* ws  = (float*)d_ws;
    float* out = (float*)d_out;
    const int n = in_sizes[0] / 3;

    prep_kernel<<<1, 64, 0, stream>>>(Bf_w, Bf_b, A1, B1_w, B1_b, A2, B2_w, B2_b, A_out, ws);
    const int blocks = (n + 15) / 16;   // 16 samples per single-wave block
    icnn_main<<<blocks, 64, 0, stream>>>(eps, ws, out, n);
}

// Round 14
// 126.418 us; speedup vs baseline: 2.1203x; 1.6782x over previous
//
#include <hip/hip_runtime.h>
#include <hip/hip_fp16.h>
#include <math.h>

#define ACT_SCALE_F (1.0f / 12.0f)
#define LOG2E_F 1.44269504088896340736f
#define LN2_F   0.69314718055994530942f

typedef __attribute__((ext_vector_type(8))) _Float16 half8;
typedef __attribute__((ext_vector_type(4))) float f32x4;
typedef __attribute__((ext_vector_type(4))) unsigned int uint4v;

// ws layout:
//  float view:
//   [0..127]   Bfq quads (legacy)   [128..255] B1q   [256..383] B2q   [384..415] spAout
//   [448..449] grad_ref (Bo_w omitted on both sides -> cancels)
//  uint view:
//   [512..2559] matrix fragment table ft: [mv(4)][u(2)][lane(64)] x 4 uints (8 fp16)
//     slot s8 of lane l: k = 16*(s8>>2) + 4*(l>>4) + (s8&3), m_or_n = 16*u + (l&15)
//     mv0=spA1, mv1=spA2 (fwd), mv2=spA2^T, mv3=spA1^T (bwd)  [R6..R13-proven sigma]
//  float view (per-lane bias quad tables in sigma slot order):
//   [2560..4607] Qf: [lane][s8] {Bf_w[2k], Bf_w[2k+1], Bf_b[k], 0},  k = sigma(s8, lane>>4)
//   [4608..6655] Q1: same for B1
//   [6656..8703] Q2: {B2_w[2k], B2_w[2k+1], B2_b[k], spAout[k]}

__device__ __forceinline__ void sp_sig(float x, float& sp, float& sig) {
    float t = __builtin_amdgcn_exp2f(-fabsf(x) * LOG2E_F);
    float u = 1.0f + t;
    float r = __builtin_amdgcn_rcpf(u);
    sp = fmaf(__builtin_amdgcn_logf(u), LN2_F, fmaxf(x, 0.0f));
    sig = (x >= 0.0f) ? r : t * r;
}

__device__ __forceinline__ float sp_only(float x) {
    float t = __builtin_amdgcn_exp2f(-fabsf(x) * LOG2E_F);
    return fmaf(__builtin_amdgcn_logf(1.0f + t), LN2_F, fmaxf(x, 0.0f));
}

__device__ __forceinline__ float sig_only(float x) {
    float t = __builtin_amdgcn_exp2f(-fabsf(x) * LOG2E_F);
    float r = __builtin_amdgcn_rcpf(1.0f + t);
    return (x >= 0.0f) ? r : t * r;
}

__global__ void prep_kernel(const float* __restrict__ Bf_w, const float* __restrict__ Bf_b,
                            const float* __restrict__ A1,
                            const float* __restrict__ B1_w, const float* __restrict__ B1_b,
                            const float* __restrict__ A2,
                            const float* __restrict__ B2_w, const float* __restrict__ B2_b,
                            const float* __restrict__ A_out,
                            float* __restrict__ ws)
{
    __shared__ float sA1[1024], sA2[1024], sAout[32];
    __shared__ float vbufA[32], vbufB[32];
    __shared__ float part0[32], part1[32];
    const int tid = threadIdx.x;  // 64 threads, 1 block

    for (int e = tid; e < 1024; e += 64) {
        sA1[e] = sp_only(A1[e]);
        sA2[e] = sp_only(A2[e]);
    }
    if (tid < 32) {
        float ao = sp_only(A_out[tid]);
        sAout[tid] = ao;
        ws[384 + tid] = ao;
    }
    __syncthreads();

    // ---- matrix fragment table (fp16), proven sigma ----
    unsigned int* wsu = (unsigned int*)ws;
    for (int e = tid; e < 512; e += 64) {
        const int mv = e >> 7, u = (e >> 6) & 1, ln = e & 63;
        const int g = ln >> 4, cc = ln & 15, m = 16 * u + cc;
        for (int q = 0; q < 4; ++q) {
            unsigned int word = 0;
            for (int h = 0; h < 2; ++h) {
                const int s8 = 2 * q + h;
                const int k = 16 * (s8 >> 2) + 4 * g + (s8 & 3);
                float v;
                if (mv == 0)      v = sA1[m * 32 + k];
                else if (mv == 1) v = sA2[m * 32 + k];
                else if (mv == 2) v = sA2[k * 32 + m];
                else              v = sA1[k * 32 + m];
                unsigned short hb = __half_as_ushort(__float2half(v));
                word |= ((unsigned int)hb) << (16 * h);
            }
            wsu[512 + 4 * e + q] = word;
        }
    }

    // ---- per-lane bias quad tables in sigma slot order ----
    for (int e = tid; e < 512; e += 64) {
        const int l = e >> 3, s8 = e & 7;
        const int g = l >> 4;
        const int k = 16 * (s8 >> 2) + 4 * g + (s8 & 3);
        ws[2560 + 4 * e]     = Bf_w[2 * k];
        ws[2560 + 4 * e + 1] = Bf_w[2 * k + 1];
        ws[2560 + 4 * e + 2] = Bf_b[k];
        ws[2560 + 4 * e + 3] = 0.f;
        ws[4608 + 4 * e]     = B1_w[2 * k];
        ws[4608 + 4 * e + 1] = B1_w[2 * k + 1];
        ws[4608 + 4 * e + 2] = B1_b[k];
        ws[4608 + 4 * e + 3] = 0.f;
        ws[6656 + 4 * e]     = B2_w[2 * k];
        ws[6656 + 4 * e + 1] = B2_w[2 * k + 1];
        ws[6656 + 4 * e + 2] = B2_b[k];
        ws[6656 + 4 * e + 3] = sAout[k];
    }

    // ---- grad_ref at z0 = 0 ----
    const int i = tid;
    float su1 = 0.f, g1 = 0.f, sb1 = 0.f;
    if (tid < 32) {
        float h0;
        sp_sig(Bf_b[i], h0, su1);
        vbufA[i] = h0;
    }
    __syncthreads();
    if (tid < 32) {
        float a1 = 0.f;
        for (int j = 0; j < 32; ++j) a1 = fmaf(vbufA[j], sA1[i * 32 + j], a1);
        float s1, sa1; sp_sig(a1, s1, sa1);
        g1 = 2.0f * ACT_SCALE_F * s1 * sa1;
        float spb1; sp_sig(B1_b[i], spb1, sb1);
        vbufB[i] = fmaf(ACT_SCALE_F * s1, s1, spb1);   // z1
    }
    __syncthreads();
    if (tid < 32) {
        float a2 = 0.f;
        for (int j = 0; j < 32; ++j) a2 = fmaf(vbufB[j], sA2[i * 32 + j], a2);
        float s2, sa2; sp_sig(a2, s2, sa2);
        float g2 = 2.0f * ACT_SCALE_F * s2 * sa2;
        float sb2 = sig_only(B2_b[i]);
        float ao = sAout[i];
        part0[i] = ao * sb2 * B2_w[i * 2 + 0];
        part1[i] = ao * sb2 * B2_w[i * 2 + 1];
        vbufA[i] = ao * g2;   // v2
    }
    __syncthreads();
    if (tid < 32) {
        float dz1 = 0.f;
        for (int ii = 0; ii < 32; ++ii) dz1 = fmaf(vbufA[ii], sA2[ii * 32 + i], dz1);
        part0[i] += dz1 * sb1 * B1_w[i * 2 + 0];
        part1[i] += dz1 * sb1 * B1_w[i * 2 + 1];
        vbufB[i] = dz1 * g1;   // v1
    }
    __syncthreads();
    if (tid < 32) {
        float dh0 = 0.f;
        for (int ii = 0; ii < 32; ++ii) dh0 = fmaf(vbufB[ii], sA1[ii * 32 + i], dh0);
        part0[i] += dh0 * su1 * Bf_w[i * 2 + 0];
        part1[i] += dh0 * su1 * Bf_w[i * 2 + 1];
    }
    __syncthreads();
    if (tid == 0) {
        float r0 = 0.f, r1 = 0.f;
        for (int j = 0; j < 32; ++j) { r0 += part0[j]; r1 += part1[j]; }
        ws[448] = r0;
        ws[449] = r1;
    }
}

// Static chain-select of MFMA result (all args compile-time in unrolled loops)
#define DSEL(ch, s8) ((ch) == 0 ? ((s8) < 4 ? dA0[(s8) & 3] : dA1[(s8) & 3]) \
                                : ((s8) < 4 ? dB0[(s8) & 3] : dB1[(s8) & 3]))

// Zero-LDS register-chain kernel (R11..R13 identity, verified), R14 change:
// DUAL CHAIN -- each wave runs two independent 16-sample groups for 2x ILP;
// every table quad / ft fragment is loaded once and used by both chains.
__global__ void __launch_bounds__(64, 2) icnn_main(
    const float* __restrict__ eps,
    const float* __restrict__ ws,
    float* __restrict__ out, int n)
{
    const int lane = threadIdx.x;       // one wave
    const int c = lane & 15;

    int idx0 = blockIdx.x * 32 + c;
    int idx1 = idx0 + 16;
    if (idx0 >= n) idx0 = n - 1;        // branchless clamp
    if (idx1 >= n) idx1 = n - 1;

    const uint4v* __restrict__ ft = (const uint4v*)((const unsigned int*)ws + 512);
    const float4* __restrict__ Qf = (const float4*)(ws + 2560) + lane * 8;
    const float4* __restrict__ Q1 = (const float4*)(ws + 4608) + lane * 8;
    const float4* __restrict__ Q2 = (const float4*)(ws + 6656) + lane * 8;
    const float gr0 = ws[448], gr1 = ws[449];

    float e11[2], e22[2], e12[2], I1v[2], I2v[2];
    e11[0] = eps[3 * idx0];  e22[0] = eps[3 * idx0 + 1];  e12[0] = eps[3 * idx0 + 2];
    e11[1] = eps[3 * idx1];  e22[1] = eps[3 * idx1 + 1];  e12[1] = eps[3 * idx1 + 2];
    #pragma unroll
    for (int ch = 0; ch < 2; ++ch) {
        I1v[ch] = e11[ch] + e22[ch];
        I2v[ch] = e11[ch] * e11[ch] + 2.f * e12[ch] * e12[ch] + e22[ch] * e22[ch];
    }

    const f32x4 z4 = {0.f, 0.f, 0.f, 0.f};
    unsigned int bwA[4], bwB[4];
    float g1v[2][8];                   // 2*ACT_SCALE * s1 * sig(a1)
    float sufx[2][8], sufy[2][8];      // sig(u_f) * {qf.x, qf.y}
    float sb1x[2][8], sb1y[2][8];      // sig(b1) * {q1.x, q1.y}
    float gx0[2] = {0.f, 0.f}, gx1[2] = {0.f, 0.f};

    // ---- L0: B-frags of h0 for both chains; cache su*qf ----
    #pragma unroll
    for (int m = 0; m < 4; ++m) {
        float pv[2][2];
        #pragma unroll
        for (int h = 0; h < 2; ++h) {
            const int s8 = 2 * m + h;
            const float4 q = Qf[s8];
            #pragma unroll
            for (int ch = 0; ch < 2; ++ch) {
                float h0, su;
                sp_sig(fmaf(I1v[ch], q.x, fmaf(I2v[ch], q.y, q.z)), h0, su);
                sufx[ch][s8] = su * q.x;
                sufy[ch][s8] = su * q.y;
                pv[ch][h] = h0;
            }
        }
        bwA[m] = __builtin_bit_cast(unsigned int, __floats2half2_rn(pv[0][0], pv[0][1]));
        bwB[m] = __builtin_bit_cast(unsigned int, __floats2half2_rn(pv[1][0], pv[1][1]));
    }
    half8 BA = __builtin_bit_cast(half8, (uint4v){bwA[0], bwA[1], bwA[2], bwA[3]});
    half8 BB = __builtin_bit_cast(half8, (uint4v){bwB[0], bwB[1], bwB[2], bwB[3]});

    // ---- fwd1: a1 = spA1 @ h0 (both chains) -> keep g1, sb1*q1; z1 packed ----
    {
        half8 A0  = __builtin_bit_cast(half8, ft[0 * 64 + lane]);
        half8 A1t = __builtin_bit_cast(half8, ft[1 * 64 + lane]);
        f32x4 dA0 = __builtin_amdgcn_mfma_f32_16x16x32_f16(A0,  BA, z4, 0, 0, 0);
        f32x4 dA1 = __builtin_amdgcn_mfma_f32_16x16x32_f16(A1t, BA, z4, 0, 0, 0);
        f32x4 dB0 = __builtin_amdgcn_mfma_f32_16x16x32_f16(A0,  BB, z4, 0, 0, 0);
        f32x4 dB1 = __builtin_amdgcn_mfma_f32_16x16x32_f16(A1t, BB, z4, 0, 0, 0);
        #pragma unroll
        for (int m = 0; m < 4; ++m) {
            float pv[2][2];
            #pragma unroll
            for (int h = 0; h < 2; ++h) {
                const int s8 = 2 * m + h;
                const float4 q = Q1[s8];
                #pragma unroll
                for (int ch = 0; ch < 2; ++ch) {
                    float a = DSEL(ch, s8);
                    float s1, sg; sp_sig(a, s1, sg);
                    g1v[ch][s8] = (2.0f * ACT_SCALE_F) * s1 * sg;
                    float spb1, sb1;
                    sp_sig(fmaf(I1v[ch], q.x, fmaf(I2v[ch], q.y, q.z)), spb1, sb1);
                    sb1x[ch][s8] = sb1 * q.x;
                    sb1y[ch][s8] = sb1 * q.y;
                    pv[ch][h] = fmaf(ACT_SCALE_F * s1, s1, spb1);
                }
            }
            bwA[m] = __builtin_bit_cast(unsigned int, __floats2half2_rn(pv[0][0], pv[0][1]));
            bwB[m] = __builtin_bit_cast(unsigned int, __floats2half2_rn(pv[1][0], pv[1][1]));
        }
        BA = __builtin_bit_cast(half8, (uint4v){bwA[0], bwA[1], bwA[2], bwA[3]});
        BB = __builtin_bit_cast(half8, (uint4v){bwB[0], bwB[1], bwB[2], bwB[3]});
    }

    // ---- fwd2: a2 = spA2 @ z1 -> gx(B2) partials; v2 packed ----
    {
        half8 A0  = __builtin_bit_cast(half8, ft[2 * 64 + lane]);
        half8 A1t = __builtin_bit_cast(half8, ft[3 * 64 + lane]);
        f32x4 dA0 = __builtin_amdgcn_mfma_f32_16x16x32_f16(A0,  BA, z4, 0, 0, 0);
        f32x4 dA1 = __builtin_amdgcn_mfma_f32_16x16x32_f16(A1t, BA, z4, 0, 0, 0);
        f32x4 dB0 = __builtin_amdgcn_mfma_f32_16x16x32_f16(A0,  BB, z4, 0, 0, 0);
        f32x4 dB1 = __builtin_amdgcn_mfma_f32_16x16x32_f16(A1t, BB, z4, 0, 0, 0);
        #pragma unroll
        for (int m = 0; m < 4; ++m) {
            float pv[2][2];
            #pragma unroll
            for (int h = 0; h < 2; ++h) {
                const int s8 = 2 * m + h;
                const float4 q = Q2[s8];
                #pragma unroll
                for (int ch = 0; ch < 2; ++ch) {
                    float a = DSEL(ch, s8);
                    float s2, sg; sp_sig(a, s2, sg);
                    float sb2 = sig_only(fmaf(I1v[ch], q.x, fmaf(I2v[ch], q.y, q.z)));
                    float ao = q.w;
                    float t = ao * sb2;
                    gx0[ch] = fmaf(t, q.x, gx0[ch]);
                    gx1[ch] = fmaf(t, q.y, gx1[ch]);
                    pv[ch][h] = ao * (2.0f * ACT_SCALE_F) * s2 * sg;
                }
            }
            bwA[m] = __builtin_bit_cast(unsigned int, __floats2half2_rn(pv[0][0], pv[0][1]));
            bwB[m] = __builtin_bit_cast(unsigned int, __floats2half2_rn(pv[1][0], pv[1][1]));
        }
        BA = __builtin_bit_cast(half8, (uint4v){bwA[0], bwA[1], bwA[2], bwA[3]});
        BB = __builtin_bit_cast(half8, (uint4v){bwB[0], bwB[1], bwB[2], bwB[3]});
    }

    // ---- bwd2: dz1 = spA2^T @ v2 -> registers only ----
    {
        half8 A0  = __builtin_bit_cast(half8, ft[4 * 64 + lane]);
        half8 A1t = __builtin_bit_cast(half8, ft[5 * 64 + lane]);
        f32x4 dA0 = __builtin_amdgcn_mfma_f32_16x16x32_f16(A0,  BA, z4, 0, 0, 0);
        f32x4 dA1 = __builtin_amdgcn_mfma_f32_16x16x32_f16(A1t, BA, z4, 0, 0, 0);
        f32x4 dB0 = __builtin_amdgcn_mfma_f32_16x16x32_f16(A0,  BB, z4, 0, 0, 0);
        f32x4 dB1 = __builtin_amdgcn_mfma_f32_16x16x32_f16(A1t, BB, z4, 0, 0, 0);
        #pragma unroll
        for (int m = 0; m < 4; ++m) {
            float pv[2][2];
            #pragma unroll
            for (int h = 0; h < 2; ++h) {
                const int s8 = 2 * m + h;
                #pragma unroll
                for (int ch = 0; ch < 2; ++ch) {
                    float dz = DSEL(ch, s8);
                    gx0[ch] = fmaf(dz, sb1x[ch][s8], gx0[ch]);
                    gx1[ch] = fmaf(dz, sb1y[ch][s8], gx1[ch]);
                    pv[ch][h] = dz * g1v[ch][s8] * (1.0f / 64.0f);
                }
            }
            bwA[m] = __builtin_bit_cast(unsigned int, __floats2half2_rn(pv[0][0], pv[0][1]));
            bwB[m] = __builtin_bit_cast(unsigned int, __floats2half2_rn(pv[1][0], pv[1][1]));
        }
        BA = __builtin_bit_cast(half8, (uint4v){bwA[0], bwA[1], bwA[2], bwA[3]});
        BB = __builtin_bit_cast(half8, (uint4v){bwB[0], bwB[1], bwB[2], bwB[3]});
    }

    // ---- bwd1: dh0/64 = spA1^T @ v1/64 -> registers only (x64) ----
    {
        half8 A0  = __builtin_bit_cast(half8, ft[6 * 64 + lane]);
        half8 A1t = __builtin_bit_cast(half8, ft[7 * 64 + lane]);
        f32x4 dA0 = __builtin_amdgcn_mfma_f32_16x16x32_f16(A0,  BA, z4, 0, 0, 0);
        f32x4 dA1 = __builtin_amdgcn_mfma_f32_16x16x32_f16(A1t, BA, z4, 0, 0, 0);
        f32x4 dB0 = __builtin_amdgcn_mfma_f32_16x16x32_f16(A0,  BB, z4, 0, 0, 0);
        f32x4 dB1 = __builtin_amdgcn_mfma_f32_16x16x32_f16(A1t, BB, z4, 0, 0, 0);
        float gf0[2] = {0.f, 0.f}, gf1[2] = {0.f, 0.f};
        #pragma unroll
        for (int s8 = 0; s8 < 8; ++s8) {
            #pragma unroll
            for (int ch = 0; ch < 2; ++ch) {
                float dh = DSEL(ch, s8);
                gf0[ch] = fmaf(dh, sufx[ch][s8], gf0[ch]);
                gf1[ch] = fmaf(dh, sufy[ch][s8], gf1[ch]);
            }
        }
        #pragma unroll
        for (int ch = 0; ch < 2; ++ch) {
            gx0[ch] = fmaf(64.f, gf0[ch], gx0[ch]);
            gx1[ch] = fmaf(64.f, gf1[ch], gx1[ch]);
        }
    }

    // ---- reduce over the 4 g-lanes; write both samples ----
    #pragma unroll
    for (int ch = 0; ch < 2; ++ch) {
        gx0[ch] += __shfl_xor(gx0[ch], 16);
        gx0[ch] += __shfl_xor(gx0[ch], 32);
        gx1[ch] += __shfl_xor(gx1[ch], 16);
        gx1[ch] += __shfl_xor(gx1[ch], 32);
    }

    if (lane < 16) {
        {
            const float dI1 = gx0[0] - gr0;
            const float dI2 = gx1[0] - gr1;
            out[3 * idx0 + 0] = fmaf(2.f * e11[0], dI2, dI1);
            out[3 * idx0 + 1] = fmaf(2.f * e22[0], dI2, dI1);
            out[3 * idx0 + 2] = 2.f * e12[0] * dI2;
        }
        {
            const float dI1 = gx0[1] - gr0;
            const float dI2 = gx1[1] - gr1;
            out[3 * idx1 + 0] = fmaf(2.f * e11[1], dI2, dI1);
            out[3 * idx1 + 1] = fmaf(2.f * e22[1], dI2, dI1);
            out[3 * idx1 + 2] = 2.f * e12[1] * dI2;
        }
    }
}

extern "C" void kernel_launch(void* const* d_in, const int* in_sizes, int n_in,
                              void* d_out, int out_size, void* d_ws, size_t ws_size,
                              hipStream_t stream)
{
    const float* eps   = (const float*)d_in[0];
    const float* Bf_w  = (const float*)d_in[1];
    const float* Bf_b  = (const float*)d_in[2];
    const float* A1    = (const float*)d_in[3];
    const float* B1_w  = (const float*)d_in[4];
    const float* B1_b  = (const float*)d_in[5];
    const float* A2    = (const float*)d_in[6];
    const float* B2_w  = (const float*)d_in[7];
    const float* B2_b  = (const float*)d_in[8];
    const float* A_out = (const float*)d_in[9];
    // d_in[10] = Bo_w (cancels in grads - grad_ref), d_in[11] = Bo_b (no grad)

    float* ws  = (float*)d_ws;
    float* out = (float*)d_out;
    const int n = in_sizes[0] / 3;

    prep_kernel<<<1, 64, 0, stream>>>(Bf_w, Bf_b, A1, B1_w, B1_b, A2, B2_w, B2_b, A_out, ws);
    const int blocks = (n + 31) / 32;   // 32 samples per single-wave block (2 chains x 16)
    icnn_main<<<blocks, 64, 0, stream>>>(eps, ws, out, n);
}